// Round 2
// baseline (1744.849 us; speedup 1.0000x reference)
//
#include <hip/hip_runtime.h>

// Problem constants
#define HWp    1024          // patches per image (32*32)
#define NPATCH 4096          // B * HWp
#define WSTR   68            // padded stride: 64 conv ch + 1 temp ch + 3 pad
#define KDIM   4096          // 64 ci * 8 * 8

// Workspace layout (float offsets)
#define WT_OFF    0u         // [4096][68] folded transposed weights
#define BIASP_OFF 278528u    // [64] folded conv biases
#define WSUM_OFF  278592u    // [64] channel-sum of conv2_w
#define MISC_OFF  278656u    // [0]=bias_t, [1]=sum(conv2_b)
#define S_OFF     278672u    // [4096] channel-sum s
#define INVT_OFF  282768u    // [4096] 1/(0.025+t)
#define PART_OFF  286864u    // [KB][4096][68] partial conv sums

// ---------------------------------------------------------------------------
// Prep: fold BN into conv weights/biases, transpose weights to [k][ch].
// ---------------------------------------------------------------------------
__global__ void prep_kernel(
    const float* __restrict__ conv1_w, const float* __restrict__ conv1_b,
    const float* __restrict__ g,  const float* __restrict__ bb,
    const float* __restrict__ m,  const float* __restrict__ v,
    const float* __restrict__ conv2_w, const float* __restrict__ conv2_b,
    const float* __restrict__ tconv_w, const float* __restrict__ tconv_b,
    const float* __restrict__ tg, const float* __restrict__ tb,
    const float* __restrict__ tm, const float* __restrict__ tv,
    float* __restrict__ ws)
{
    float* Wt = ws + WT_OFF;
    if (blockIdx.x < 16) {
        int k = blockIdx.x * 256 + threadIdx.x;   // 0..4095
        float At = tg[0] / sqrtf(tv[0] + 1e-5f);
        #pragma unroll 8
        for (int c = 0; c < 64; ++c) {
            float A = g[c] / sqrtf(v[c] + 1e-5f);
            Wt[(size_t)k * WSTR + c] = A * conv1_w[(size_t)c * KDIM + k];
        }
        Wt[(size_t)k * WSTR + 64] = At * tconv_w[k];
        Wt[(size_t)k * WSTR + 65] = 0.0f;
        Wt[(size_t)k * WSTR + 66] = 0.0f;
        Wt[(size_t)k * WSTR + 67] = 0.0f;
    } else {
        int t = threadIdx.x;
        if (t < 64) {
            float A = g[t] / sqrtf(v[t] + 1e-5f);
            ws[BIASP_OFF + t] = A * (conv1_b[t] - m[t]) + bb[t];
            float s = 0.f;
            for (int co = 0; co < 64; ++co) s += conv2_w[co * 64 + t];
            ws[WSUM_OFF + t] = s;
        } else if (t == 64) {
            float At = tg[0] / sqrtf(tv[0] + 1e-5f);
            ws[MISC_OFF + 0] = At * (tconv_b[0] - tm[0]) + tb[0];
            float bs = 0.f;
            for (int c = 0; c < 64; ++c) bs += conv2_b[c];
            ws[MISC_OFF + 1] = bs;
        }
    }
}

// ---------------------------------------------------------------------------
// Patch conv, fp32. Block = 256 threads = 4 waves. Lane = patch (64 patches
// per block). Wave w computes channels [w*16, w*16+17) (17-ch overlap rows
// recompute identical values - benign). K split across blockIdx.y (KB chunks
// of nci input channels). Weights double-buffered in LDS (17KB per ci),
// staged reg-style: loads issued before compute, ds_write after (T14).
// Inner loop: wave-uniform ds_read_b128 broadcasts + 17 FMAs per kx.
// Epilogue: transpose acc via LDS, store partials as contiguous float4 rows.
// ---------------------------------------------------------------------------
__global__ __launch_bounds__(256, 2) void conv_kernel(
    const float* __restrict__ x, const float* __restrict__ ws_ro,
    float* __restrict__ part, int nci)
{
    __shared__ float lds[8704];   // 2 x [64][68] weight buffers / [68][65] trans
    int t    = threadIdx.x;
    int wv   = __builtin_amdgcn_readfirstlane(t >> 6);
    int lane = t & 63;
    int mb   = blockIdx.x;        // 64 patch-blocks
    int kb   = blockIdx.y;        // KB K-chunks
    int gp   = mb * 64 + lane;
    int b    = mb >> 4;           // 16 blocks per image
    int py   = (gp >> 5) & 31;
    int px   = gp & 31;
    int cbase = wv * 16;

    const float* Wt      = ws_ro + WT_OFF;
    const float* wchunk0 = Wt + (size_t)(kb * nci) * 64 * WSTR;

    float acc[17];
    #pragma unroll
    for (int i = 0; i < 17; ++i) acc[i] = 0.f;

    const float* xbase = x + ((size_t)(b * 64) * 256 + py * 8) * 256 + px * 8;

    // prologue: stage ci chunk 0 into buffer 0
    float4 stg[5];
    {
        const float4* src = (const float4*)wchunk0;
        #pragma unroll
        for (int i = 0; i < 4; ++i) stg[i] = src[i * 256 + t];
        if (t < 64) stg[4] = src[1024 + t];
        float4* dst = (float4*)lds;
        #pragma unroll
        for (int i = 0; i < 4; ++i) dst[i * 256 + t] = stg[i];
        if (t < 64) dst[1024 + t] = stg[4];
    }
    __syncthreads();

    for (int cii = 0; cii < nci; ++cii) {
        int buf = cii & 1;
        // issue next chunk's global loads early (latency hides under compute)
        if (cii + 1 < nci) {
            const float4* src = (const float4*)(wchunk0 + (size_t)(cii + 1) * 64 * WSTR);
            #pragma unroll
            for (int i = 0; i < 4; ++i) stg[i] = src[i * 256 + t];
            if (t < 64) stg[4] = src[1024 + t];
        }
        int ci = kb * nci + cii;
        const float* xc = xbase + (size_t)ci * 65536;
        const float* wb = lds + buf * 4352;
        #pragma unroll
        for (int ky = 0; ky < 8; ++ky) {
            const float4* xr = (const float4*)(xc + ky * 256);
            float4 a0 = xr[0];
            float4 a1 = xr[1];
            float xv[8] = {a0.x, a0.y, a0.z, a0.w, a1.x, a1.y, a1.z, a1.w};
            #pragma unroll
            for (int kx = 0; kx < 8; ++kx) {
                const float* wr = wb + (ky * 8 + kx) * WSTR + cbase;
                float4 w0 = *(const float4*)(wr);
                float4 w1 = *(const float4*)(wr + 4);
                float4 w2 = *(const float4*)(wr + 8);
                float4 w3 = *(const float4*)(wr + 12);
                float  w4 = wr[16];
                float xk = xv[kx];
                acc[0]  = fmaf(w0.x, xk, acc[0]);
                acc[1]  = fmaf(w0.y, xk, acc[1]);
                acc[2]  = fmaf(w0.z, xk, acc[2]);
                acc[3]  = fmaf(w0.w, xk, acc[3]);
                acc[4]  = fmaf(w1.x, xk, acc[4]);
                acc[5]  = fmaf(w1.y, xk, acc[5]);
                acc[6]  = fmaf(w1.z, xk, acc[6]);
                acc[7]  = fmaf(w1.w, xk, acc[7]);
                acc[8]  = fmaf(w2.x, xk, acc[8]);
                acc[9]  = fmaf(w2.y, xk, acc[9]);
                acc[10] = fmaf(w2.z, xk, acc[10]);
                acc[11] = fmaf(w2.w, xk, acc[11]);
                acc[12] = fmaf(w3.x, xk, acc[12]);
                acc[13] = fmaf(w3.y, xk, acc[13]);
                acc[14] = fmaf(w3.z, xk, acc[14]);
                acc[15] = fmaf(w3.w, xk, acc[15]);
                acc[16] = fmaf(w4,   xk, acc[16]);
            }
        }
        // write next buffer (no one reads buf^1 this iteration - safe pre-barrier)
        if (cii + 1 < nci) {
            float4* dst = (float4*)(lds + (buf ^ 1) * 4352);
            #pragma unroll
            for (int i = 0; i < 4; ++i) dst[i * 256 + t] = stg[i];
            if (t < 64) dst[1024 + t] = stg[4];
        }
        __syncthreads();
    }

    // transpose acc via LDS: trans[c][p] with pad-65 rows (conflict-free)
    #pragma unroll
    for (int i = 0; i < 17; ++i)
        lds[(cbase + i) * 65 + lane] = acc[i];
    __syncthreads();

    // store partials: part[kb][gp][c], contiguous float4 rows
    float* prow = part + ((size_t)kb * NPATCH + (size_t)mb * 64) * WSTR;
    #pragma unroll
    for (int i = 0; i < 4; ++i) {
        int idx4 = i * 256 + t;
        int p = idx4 / 17, c4 = idx4 % 17;
        float4 vv;
        vv.x = lds[(c4 * 4 + 0) * 65 + p];
        vv.y = lds[(c4 * 4 + 1) * 65 + p];
        vv.z = lds[(c4 * 4 + 2) * 65 + p];
        vv.w = lds[(c4 * 4 + 3) * 65 + p];
        ((float4*)prow)[idx4] = vv;
    }
    if (t < 64) {
        int idx4 = 1024 + t;
        int p = idx4 / 17, c4 = idx4 % 17;
        float4 vv;
        vv.x = lds[(c4 * 4 + 0) * 65 + p];
        vv.y = lds[(c4 * 4 + 1) * 65 + p];
        vv.z = lds[(c4 * 4 + 2) * 65 + p];
        vv.w = lds[(c4 * 4 + 3) * 65 + p];
        ((float4*)prow)[idx4] = vv;
    }
}

// ---------------------------------------------------------------------------
// Finalize: wave per patch, lane = channel. Sum K-chunks, bias, ReLU,
// dot with wsum via shuffle reduce -> s; temperature channel -> invT.
// ---------------------------------------------------------------------------
__global__ __launch_bounds__(256) void finalize_kernel(
    float* ws, const float* part, int KB)
{
    int t = threadIdx.x;
    int wv = t >> 6;
    int lane = t & 63;
    int gp = blockIdx.x * 4 + wv;     // 1024 blocks -> 4096 patches
    float a = 0.f;
    for (int kb = 0; kb < KB; ++kb)
        a += part[((size_t)kb * NPATCH + gp) * WSTR + lane];
    float h = fmaxf(a + ws[BIASP_OFF + lane], 0.f) * ws[WSUM_OFF + lane];
    #pragma unroll
    for (int off = 32; off; off >>= 1)
        h += __shfl_xor(h, off, 64);
    if (lane == 0) {
        float ta = 0.f;
        for (int kb = 0; kb < KB; ++kb)
            ta += part[((size_t)kb * NPATCH + gp) * WSTR + 64];
        float tval = fmaxf(ta + ws[MISC_OFF + 0], 0.f);
        ws[S_OFF + gp]    = h + ws[MISC_OFF + 1];
        ws[INVT_OFF + gp] = 1.0f / (0.025f + tval);
    }
}

// ---------------------------------------------------------------------------
// Fused 4-iteration softmax. One WAVE per query patch row; 1024 logits in
// 16 registers/lane; wave-shuffle reductions only.
// ---------------------------------------------------------------------------
__global__ __launch_bounds__(256) void softmax_kernel(
    const float* __restrict__ ws_ro, float* __restrict__ out)
{
    const float* sArr = ws_ro + S_OFF;
    const float* invT = ws_ro + INVT_OFF;
    int t    = threadIdx.x;
    int wv   = t >> 6;
    int lane = t & 63;
    int gp   = blockIdx.x * 4 + wv;   // 0..4095
    int b    = gp >> 10;
    int p    = gp & 1023;
    float sq = sArr[gp];
    float iT = invT[gp];
    const float4* srow = (const float4*)(sArr + (size_t)b * HWp);

    float L[16];
    #pragma unroll
    for (int c4 = 0; c4 < 4; ++c4) {
        float4 sv = srow[c4 * 64 + lane];
        int q0 = c4 * 256 + lane * 4;
        float d0 = sq - sv.x, d1 = sq - sv.y, d2 = sq - sv.z, d3 = sq - sv.w;
        L[c4*4+0] = -d0 * d0 * iT;
        L[c4*4+1] = -d1 * d1 * iT;
        L[c4*4+2] = -d2 * d2 * iT;
        L[c4*4+3] = -d3 * d3 * iT;
        if (q0 + 0 == p) L[c4*4+0] -= 1000.f * iT;
        if (q0 + 1 == p) L[c4*4+1] -= 1000.f * iT;
        if (q0 + 2 == p) L[c4*4+2] -= 1000.f * iT;
        if (q0 + 3 == p) L[c4*4+3] -= 1000.f * iT;
    }

    size_t rowOff = (size_t)gp * HWp;
    #pragma unroll 1
    for (int it = 0; it < 4; ++it) {
        float mx = L[0];
        #pragma unroll
        for (int j = 1; j < 16; ++j) mx = fmaxf(mx, L[j]);
        #pragma unroll
        for (int off = 32; off; off >>= 1)
            mx = fmaxf(mx, __shfl_xor(mx, off, 64));
        float e[16];
        float sum = 0.f;
        #pragma unroll
        for (int j = 0; j < 16; ++j) { e[j] = expf(L[j] - mx); sum += e[j]; }
        #pragma unroll
        for (int off = 32; off; off >>= 1)
            sum += __shfl_xor(sum, off, 64);
        float r = 1.0f / sum;
        #pragma unroll
        for (int j = 0; j < 16; ++j) e[j] *= r;
        float4* orow = (float4*)(out + (size_t)it * NPATCH * HWp + rowOff);
        #pragma unroll
        for (int c4 = 0; c4 < 4; ++c4) {
            float4 o;
            o.x = e[c4*4+0]; o.y = e[c4*4+1]; o.z = e[c4*4+2]; o.w = e[c4*4+3];
            orow[c4 * 64 + lane] = o;
        }
        if (it < 3) {
            #pragma unroll
            for (int j = 0; j < 16; ++j)
                L[j] += iT * logf(1.0f - e[j] + 1e-45f);
        }
    }
}

// ---------------------------------------------------------------------------
extern "C" void kernel_launch(void* const* d_in, const int* in_sizes, int n_in,
                              void* d_out, int out_size, void* d_ws, size_t ws_size,
                              hipStream_t stream)
{
    (void)in_sizes; (void)n_in; (void)out_size;
    const float* x       = (const float*)d_in[0];
    const float* conv1_w = (const float*)d_in[1];
    const float* conv1_b = (const float*)d_in[2];
    const float* bn1_g   = (const float*)d_in[3];
    const float* bn1_b   = (const float*)d_in[4];
    const float* bn1_m   = (const float*)d_in[5];
    const float* bn1_v   = (const float*)d_in[6];
    const float* conv2_w = (const float*)d_in[7];
    const float* conv2_b = (const float*)d_in[8];
    const float* tconv_w = (const float*)d_in[9];
    const float* tconv_b = (const float*)d_in[10];
    const float* bnt_g   = (const float*)d_in[11];
    const float* bnt_b   = (const float*)d_in[12];
    const float* bnt_m   = (const float*)d_in[13];
    const float* bnt_v   = (const float*)d_in[14];

    float* ws  = (float*)d_ws;
    float* out = (float*)d_out;

    // Largest K-split whose partial buffer fits the workspace.
    int KB = 8;
    while (KB > 1 &&
           (size_t)(PART_OFF + (size_t)KB * NPATCH * WSTR) * 4 > ws_size)
        KB >>= 1;
    int nci = 64 / KB;

    prep_kernel<<<dim3(17), dim3(256), 0, stream>>>(
        conv1_w, conv1_b, bn1_g, bn1_b, bn1_m, bn1_v,
        conv2_w, conv2_b, tconv_w, tconv_b, bnt_g, bnt_b, bnt_m, bnt_v, ws);

    conv_kernel<<<dim3(64, KB), dim3(256), 0, stream>>>(
        x, ws, ws + PART_OFF, nci);

    finalize_kernel<<<dim3(1024), dim3(256), 0, stream>>>(ws, ws + PART_OFF, KB);

    softmax_kernel<<<dim3(1024), dim3(256), 0, stream>>>(ws, out);
}

// Round 3
// 86.054 us; speedup vs baseline: 20.2762x; 20.2762x over previous
//
#include <hip/hip_runtime.h>

// Problem constants
#define HWp    1024          // patches per image (32*32)
#define NPATCH 4096          // B * HWp
#define WSTR   68            // padded stride: 64 conv ch + 1 temp ch + 3 pad
#define KDIM   4096          // 64 ci * 8 * 8

// Workspace layout (float offsets)
#define WT_OFF    0u         // [4096][68] folded transposed weights
#define BIASP_OFF 278528u    // [64] folded conv biases
#define WSUM_OFF  278592u    // [64] channel-sum of conv2_w
#define MISC_OFF  278656u    // [0]=bias_t, [1]=sum(conv2_b)
#define S_OFF     278672u    // [4096] channel-sum s
#define INVT_OFF  282768u    // [4096] 1/(0.025+t)
#define PART_OFF  286864u    // [KB][4096][68] partial conv sums

typedef __attribute__((address_space(1))) const void GVOID;
typedef __attribute__((address_space(3))) void LVOID;

// ---------------------------------------------------------------------------
// Prep: fold BN into conv weights/biases, transpose weights to [k][ch].
// ---------------------------------------------------------------------------
__global__ void prep_kernel(
    const float* __restrict__ conv1_w, const float* __restrict__ conv1_b,
    const float* __restrict__ g,  const float* __restrict__ bb,
    const float* __restrict__ m,  const float* __restrict__ v,
    const float* __restrict__ conv2_w, const float* __restrict__ conv2_b,
    const float* __restrict__ tconv_w, const float* __restrict__ tconv_b,
    const float* __restrict__ tg, const float* __restrict__ tb,
    const float* __restrict__ tm, const float* __restrict__ tv,
    float* __restrict__ ws)
{
    float* Wt = ws + WT_OFF;
    if (blockIdx.x < 16) {
        int k = blockIdx.x * 256 + threadIdx.x;   // 0..4095
        float At = tg[0] / sqrtf(tv[0] + 1e-5f);
        #pragma unroll 8
        for (int c = 0; c < 64; ++c) {
            float A = g[c] / sqrtf(v[c] + 1e-5f);
            Wt[(size_t)k * WSTR + c] = A * conv1_w[(size_t)c * KDIM + k];
        }
        Wt[(size_t)k * WSTR + 64] = At * tconv_w[k];
        Wt[(size_t)k * WSTR + 65] = 0.0f;
        Wt[(size_t)k * WSTR + 66] = 0.0f;
        Wt[(size_t)k * WSTR + 67] = 0.0f;
    } else {
        int t = threadIdx.x;
        if (t < 64) {
            float A = g[t] / sqrtf(v[t] + 1e-5f);
            ws[BIASP_OFF + t] = A * (conv1_b[t] - m[t]) + bb[t];
            float s = 0.f;
            for (int co = 0; co < 64; ++co) s += conv2_w[co * 64 + t];
            ws[WSUM_OFF + t] = s;
        } else if (t == 64) {
            float At = tg[0] / sqrtf(tv[0] + 1e-5f);
            ws[MISC_OFF + 0] = At * (tconv_b[0] - tm[0]) + tb[0];
            float bs = 0.f;
            for (int c = 0; c < 64; ++c) bs += conv2_b[c];
            ws[MISC_OFF + 1] = bs;
        }
    }
}

// ---------------------------------------------------------------------------
// Patch conv, fp32. Block = 256 threads = 4 waves, 128 patches per block
// (2 per lane). Wave w handles channels [16w,16w+16) + temp (redundant).
// Weights double-buffered in LDS via global_load_lds (async, zero staging
// VGPRs). Inner loop: 4x ds_read_b128 + 1x ds_read_b32 broadcast + 34 FMA.
// All accumulators are NAMED SCALARS - nothing can be lowered to scratch.
// ---------------------------------------------------------------------------
// stage one ci-chunk (4352 floats = 1088 x 16B) into LDS at float-offset DSTF
#define STAGE(DSTF, SRCP)                                                     \
    do {                                                                      \
        const float* _s = (SRCP);                                             \
        _Pragma("unroll")                                                     \
        for (int _r = 0; _r < 5; ++_r) {                                      \
            int _i = _r * 256 + t;                                            \
            if (_i < 1088)                                                    \
                __builtin_amdgcn_global_load_lds(                             \
                    (GVOID*)(_s + (size_t)_i * 4),                            \
                    (LVOID*)&lds[(DSTF) + _i * 4], 16, 0, 0);                 \
        }                                                                     \
    } while (0)

#define FMAB(XK0, XK1, WROW)                                                  \
    do {                                                                      \
        const float* _w = (WROW);                                             \
        float4 _w0 = *(const float4*)(_w + cbase);                            \
        float4 _w1 = *(const float4*)(_w + cbase + 4);                        \
        float4 _w2 = *(const float4*)(_w + cbase + 8);                        \
        float4 _w3 = *(const float4*)(_w + cbase + 12);                       \
        float  _wt = _w[64];                                                  \
        float _x0 = (XK0), _x1 = (XK1);                                       \
        a0  = fmaf(_w0.x, _x0, a0);   b0  = fmaf(_w0.x, _x1, b0);             \
        a1  = fmaf(_w0.y, _x0, a1);   b1  = fmaf(_w0.y, _x1, b1);             \
        a2  = fmaf(_w0.z, _x0, a2);   b2  = fmaf(_w0.z, _x1, b2);             \
        a3  = fmaf(_w0.w, _x0, a3);   b3  = fmaf(_w0.w, _x1, b3);             \
        a4  = fmaf(_w1.x, _x0, a4);   b4  = fmaf(_w1.x, _x1, b4);             \
        a5  = fmaf(_w1.y, _x0, a5);   b5  = fmaf(_w1.y, _x1, b5);             \
        a6  = fmaf(_w1.z, _x0, a6);   b6  = fmaf(_w1.z, _x1, b6);             \
        a7  = fmaf(_w1.w, _x0, a7);   b7  = fmaf(_w1.w, _x1, b7);             \
        a8  = fmaf(_w2.x, _x0, a8);   b8  = fmaf(_w2.x, _x1, b8);             \
        a9  = fmaf(_w2.y, _x0, a9);   b9  = fmaf(_w2.y, _x1, b9);             \
        a10 = fmaf(_w2.z, _x0, a10);  b10 = fmaf(_w2.z, _x1, b10);            \
        a11 = fmaf(_w2.w, _x0, a11);  b11 = fmaf(_w2.w, _x1, b11);            \
        a12 = fmaf(_w3.x, _x0, a12);  b12 = fmaf(_w3.x, _x1, b12);            \
        a13 = fmaf(_w3.y, _x0, a13);  b13 = fmaf(_w3.y, _x1, b13);            \
        a14 = fmaf(_w3.z, _x0, a14);  b14 = fmaf(_w3.z, _x1, b14);            \
        a15 = fmaf(_w3.w, _x0, a15);  b15 = fmaf(_w3.w, _x1, b15);            \
        at  = fmaf(_wt, _x0, at);     bt  = fmaf(_wt, _x1, bt);               \
    } while (0)

__global__ __launch_bounds__(256, 2) void conv_kernel(
    const float* __restrict__ x, const float* __restrict__ ws_ro,
    float* __restrict__ part, int nci)
{
    __shared__ __align__(16) float lds[8772];  // 2x4352 stage / 68x129 transpose
    int t    = threadIdx.x;
    int wv   = __builtin_amdgcn_readfirstlane(t >> 6);
    int lane = t & 63;
    int mb   = blockIdx.x;        // 32 patch-blocks of 128
    int kb   = blockIdx.y;        // KB K-chunks
    int b    = mb >> 3;           // 8 blocks per image
    int gp0  = mb * 128 + lane;   // lane's first patch (second = +64)
    int py0  = (gp0 >> 5) & 31;
    int px0  = gp0 & 31;
    int cbase = wv * 16;

    const float* wchunk = ws_ro + WT_OFF + (size_t)(kb * nci) * 64 * WSTR;
    const float* xpat   = x + ((size_t)(b * 64 + kb * nci) << 16)
                            + py0 * 2048 + px0 * 8;

    float a0=0,a1=0,a2=0,a3=0,a4=0,a5=0,a6=0,a7=0;
    float a8=0,a9=0,a10=0,a11=0,a12=0,a13=0,a14=0,a15=0;
    float b0=0,b1=0,b2=0,b3=0,b4=0,b5=0,b6=0,b7=0;
    float b8=0,b9=0,b10=0,b11=0,b12=0,b13=0,b14=0,b15=0;
    float at=0, bt=0;

    STAGE(0, wchunk);
    __syncthreads();

    for (int cii = 0; cii < nci; ++cii) {
        int bufF = (cii & 1) * 4352;
        if (cii + 1 < nci)
            STAGE(bufF ^ 4352, wchunk + (size_t)(cii + 1) * 4352);
        const float* xc0 = xpat + ((size_t)cii << 16);
        #pragma unroll
        for (int ky = 0; ky < 8; ++ky) {
            float4 p00 = *(const float4*)(xc0 + ky * 256);
            float4 p01 = *(const float4*)(xc0 + ky * 256 + 4);
            float4 p10 = *(const float4*)(xc0 + 4096 + ky * 256);
            float4 p11 = *(const float4*)(xc0 + 4096 + ky * 256 + 4);
            const float* wrow = &lds[bufF + ky * 8 * WSTR];
            FMAB(p00.x, p10.x, wrow);
            FMAB(p00.y, p10.y, wrow + WSTR);
            FMAB(p00.z, p10.z, wrow + 2 * WSTR);
            FMAB(p00.w, p10.w, wrow + 3 * WSTR);
            FMAB(p01.x, p11.x, wrow + 4 * WSTR);
            FMAB(p01.y, p11.y, wrow + 5 * WSTR);
            FMAB(p01.z, p11.z, wrow + 6 * WSTR);
            FMAB(p01.w, p11.w, wrow + 7 * WSTR);
        }
        __syncthreads();   // drains vmcnt (next stage landed), frees buffer
    }

    // transpose via LDS: trans[ch][patch] with stride 129 (conflict-free)
    #define STROW(I, VA, VB)                                   \
        lds[(cbase + (I)) * 129 + lane] = VA;                  \
        lds[(cbase + (I)) * 129 + 64 + lane] = VB;
    STROW(0,a0,b0)   STROW(1,a1,b1)   STROW(2,a2,b2)   STROW(3,a3,b3)
    STROW(4,a4,b4)   STROW(5,a5,b5)   STROW(6,a6,b6)   STROW(7,a7,b7)
    STROW(8,a8,b8)   STROW(9,a9,b9)   STROW(10,a10,b10) STROW(11,a11,b11)
    STROW(12,a12,b12) STROW(13,a13,b13) STROW(14,a14,b14) STROW(15,a15,b15)
    #undef STROW
    if (wv == 0) {
        lds[64 * 129 + lane] = at;
        lds[64 * 129 + 64 + lane] = bt;
    } else {
        int zr = 64 + wv;            // rows 65..67 = zero pad
        lds[zr * 129 + lane] = 0.f;
        lds[zr * 129 + 64 + lane] = 0.f;
    }
    __syncthreads();

    // store partials: part[kb][gp][ch], contiguous float4 rows
    float* prow = part + ((size_t)kb * NPATCH + (size_t)mb * 128) * WSTR;
    for (int r = 0; r < 9; ++r) {
        int idx = r * 256 + t;
        if (idx < 2176) {
            int p = idx / 17, c4 = idx - p * 17;
            float4 vv;
            vv.x = lds[(c4 * 4 + 0) * 129 + p];
            vv.y = lds[(c4 * 4 + 1) * 129 + p];
            vv.z = lds[(c4 * 4 + 2) * 129 + p];
            vv.w = lds[(c4 * 4 + 3) * 129 + p];
            ((float4*)prow)[idx] = vv;
        }
    }
}

// ---------------------------------------------------------------------------
// Finalize: wave per patch, lane = channel. Sum K-chunks, bias, ReLU,
// dot with wsum via shuffle reduce -> s; temperature channel -> invT.
// ---------------------------------------------------------------------------
__global__ __launch_bounds__(256) void finalize_kernel(
    float* ws, const float* part, int KB)
{
    int t = threadIdx.x;
    int wv = t >> 6;
    int lane = t & 63;
    int gp = blockIdx.x * 4 + wv;     // 1024 blocks -> 4096 patches
    float a = 0.f;
    for (int kb = 0; kb < KB; ++kb)
        a += part[((size_t)kb * NPATCH + gp) * WSTR + lane];
    float h = fmaxf(a + ws[BIASP_OFF + lane], 0.f) * ws[WSUM_OFF + lane];
    #pragma unroll
    for (int off = 32; off; off >>= 1)
        h += __shfl_xor(h, off, 64);
    if (lane == 0) {
        float ta = 0.f;
        for (int kb = 0; kb < KB; ++kb)
            ta += part[((size_t)kb * NPATCH + gp) * WSTR + 64];
        float tval = fmaxf(ta + ws[MISC_OFF + 0], 0.f);
        ws[S_OFF + gp]    = h + ws[MISC_OFF + 1];
        ws[INVT_OFF + gp] = 1.0f / (0.025f + tval);
    }
}

// ---------------------------------------------------------------------------
// Fused 4-iteration softmax. One WAVE per query patch row; 1024 logits in
// 16 registers/lane; wave-shuffle reductions only.
// ---------------------------------------------------------------------------
__global__ __launch_bounds__(256) void softmax_kernel(
    const float* __restrict__ ws_ro, float* __restrict__ out)
{
    const float* sArr = ws_ro + S_OFF;
    const float* invT = ws_ro + INVT_OFF;
    int t    = threadIdx.x;
    int wv   = t >> 6;
    int lane = t & 63;
    int gp   = blockIdx.x * 4 + wv;   // 0..4095
    int b    = gp >> 10;
    int p    = gp & 1023;
    float sq = sArr[gp];
    float iT = invT[gp];
    const float4* srow = (const float4*)(sArr + (size_t)b * HWp);

    float L[16];
    #pragma unroll
    for (int c4 = 0; c4 < 4; ++c4) {
        float4 sv = srow[c4 * 64 + lane];
        int q0 = c4 * 256 + lane * 4;
        float d0 = sq - sv.x, d1 = sq - sv.y, d2 = sq - sv.z, d3 = sq - sv.w;
        L[c4*4+0] = -d0 * d0 * iT;
        L[c4*4+1] = -d1 * d1 * iT;
        L[c4*4+2] = -d2 * d2 * iT;
        L[c4*4+3] = -d3 * d3 * iT;
        if (q0 + 0 == p) L[c4*4+0] -= 1000.f * iT;
        if (q0 + 1 == p) L[c4*4+1] -= 1000.f * iT;
        if (q0 + 2 == p) L[c4*4+2] -= 1000.f * iT;
        if (q0 + 3 == p) L[c4*4+3] -= 1000.f * iT;
    }

    size_t rowOff = (size_t)gp * HWp;
    #pragma unroll 1
    for (int it = 0; it < 4; ++it) {
        float mx = L[0];
        #pragma unroll
        for (int j = 1; j < 16; ++j) mx = fmaxf(mx, L[j]);
        #pragma unroll
        for (int off = 32; off; off >>= 1)
            mx = fmaxf(mx, __shfl_xor(mx, off, 64));
        float e[16];
        float sum = 0.f;
        #pragma unroll
        for (int j = 0; j < 16; ++j) { e[j] = __expf(L[j] - mx); sum += e[j]; }
        #pragma unroll
        for (int off = 32; off; off >>= 1)
            sum += __shfl_xor(sum, off, 64);
        float r = 1.0f / sum;
        #pragma unroll
        for (int j = 0; j < 16; ++j) e[j] *= r;
        float4* orow = (float4*)(out + (size_t)it * NPATCH * HWp + rowOff);
        #pragma unroll
        for (int c4 = 0; c4 < 4; ++c4) {
            float4 o;
            o.x = e[c4*4+0]; o.y = e[c4*4+1]; o.z = e[c4*4+2]; o.w = e[c4*4+3];
            orow[c4 * 64 + lane] = o;
        }
        if (it < 3) {
            #pragma unroll
            for (int j = 0; j < 16; ++j)
                L[j] += iT * __logf(1.0f - e[j] + 1e-45f);
        }
    }
}

// ---------------------------------------------------------------------------
extern "C" void kernel_launch(void* const* d_in, const int* in_sizes, int n_in,
                              void* d_out, int out_size, void* d_ws, size_t ws_size,
                              hipStream_t stream)
{
    (void)in_sizes; (void)n_in; (void)out_size;
    const float* x       = (const float*)d_in[0];
    const float* conv1_w = (const float*)d_in[1];
    const float* conv1_b = (const float*)d_in[2];
    const float* bn1_g   = (const float*)d_in[3];
    const float* bn1_b   = (const float*)d_in[4];
    const float* bn1_m   = (const float*)d_in[5];
    const float* bn1_v   = (const float*)d_in[6];
    const float* conv2_w = (const float*)d_in[7];
    const float* conv2_b = (const float*)d_in[8];
    const float* tconv_w = (const float*)d_in[9];
    const float* tconv_b = (const float*)d_in[10];
    const float* bnt_g   = (const float*)d_in[11];
    const float* bnt_b   = (const float*)d_in[12];
    const float* bnt_m   = (const float*)d_in[13];
    const float* bnt_v   = (const float*)d_in[14];

    float* ws  = (float*)d_ws;
    float* out = (float*)d_out;

    // Largest K-split whose partial buffer fits the workspace.
    int KB = 32;
    while (KB > 1 &&
           (size_t)(PART_OFF + (size_t)KB * NPATCH * WSTR) * 4 > ws_size)
        KB >>= 1;
    int nci = 64 / KB;

    prep_kernel<<<dim3(17), dim3(256), 0, stream>>>(
        conv1_w, conv1_b, bn1_g, bn1_b, bn1_m, bn1_v,
        conv2_w, conv2_b, tconv_w, tconv_b, bnt_g, bnt_b, bnt_m, bnt_v, ws);

    conv_kernel<<<dim3(32, KB), dim3(256), 0, stream>>>(
        x, ws, ws + PART_OFF, nci);

    finalize_kernel<<<dim3(1024), dim3(256), 0, stream>>>(ws, ws + PART_OFF, KB);

    softmax_kernel<<<dim3(1024), dim3(256), 0, stream>>>(ws, out);
}